// Round 6
// baseline (29.607 us; speedup 1.0000x reference)
//
#include <hip/hip_runtime.h>

// LIF neuron scan: v' = v*0.5 + x + r; s = (v'>0); v = s ? 0 : v'
// T=100 sequential steps, B*N = 131072 independent chains.
// Irreducible traffic: read 105 MB + write 52 MB = 157 MB.
//
// Config sweep result: 4B/8waves = 30.3 us, 8B/4waves = 28.1 us (best),
// 16B/2waves = 29.0 us; explicit SW pipeline neutral. This is R0's winning
// float2 mapping + nontemporal stores (isolated this time): the output is
// written once and never read, and warm-replay counters show reads are
// L3-resident (hbm traffic = writes only) — nt stores keep the 52 MB/replay
// output allocation from displacing input lines in L2/L3.
//
// Note: __builtin_nontemporal_store requires a native clang vector type,
// not HIP_vector_type<float,2> — use ext_vector_type(2).

#define TAU 0.5f

typedef float v2f __attribute__((ext_vector_type(2)));

__global__ __launch_bounds__(256) void lif_scan_kernel(
    const v2f* __restrict__ inp,
    const v2f* __restrict__ rec,
    v2f* __restrict__ out,
    int n2,   // float2 lanes per timestep (B*N/2) = 65536
    int T)    // 100
{
    const int i = blockIdx.x * blockDim.x + threadIdx.x;
    if (i >= n2) return;

    float vx = 0.0f, vy = 0.0f;

    #pragma unroll 4
    for (int t = 0; t < T; ++t) {
        const size_t off = (size_t)t * (size_t)n2 + (size_t)i;
        const v2f x = inp[off];
        const v2f r = rec[off];

        // v*0.5 is exact (pow2), so fma contraction cannot change the
        // rounded result vs numpy's (v*0.5 + x) + r -> spike test exact.
        vx = vx * TAU + x.x + r.x;
        vy = vy * TAU + x.y + r.y;

        v2f s;
        s.x = (vx > 0.0f) ? 1.0f : 0.0f;
        s.y = (vy > 0.0f) ? 1.0f : 0.0f;

        vx = (vx > 0.0f) ? 0.0f : vx;
        vy = (vy > 0.0f) ? 0.0f : vy;

        __builtin_nontemporal_store(s, &out[off]);
    }
}

extern "C" void kernel_launch(void* const* d_in, const int* in_sizes, int n_in,
                              void* d_out, int out_size, void* d_ws, size_t ws_size,
                              hipStream_t stream) {
    const float* inp = (const float*)d_in[0];
    const float* rec = (const float*)d_in[1];
    float* out = (float*)d_out;

    const int T = 100;
    const int per_t = in_sizes[0] / T;   // B*N = 131072
    const int n2 = per_t / 2;            // 65536 float2 lanes

    const int block = 256;
    const int grid = (n2 + block - 1) / block;   // 256 blocks -> 1 per CU

    lif_scan_kernel<<<grid, block, 0, stream>>>(
        (const v2f*)inp, (const v2f*)rec, (v2f*)out, n2, T);
}

// Round 7
// 29.250 us; speedup vs baseline: 1.0122x; 1.0122x over previous
//
#include <hip/hip_runtime.h>

// LIF neuron scan: v' = v*0.5 + x + r; s = (v'>0); v = s ? 0 : v'
// T=100 sequential steps, B*N = 131072 independent chains.
// Irreducible traffic: read 105 MB + write 52 MB = 157 MB.
//
// FINAL (= R0, the sweep's best at 28.1 us = 89% of the 6.3 TB/s copy
// ceiling, ~91% of the ~10 B/cy/CU per-CU memory-path limit).
// Sweep: 4B/8waves=30.3, 8B/4waves=28.1 (this), 16B/2waves=29.0,
// +SW-pipeline=28.9, +nontemporal=29.6. Memory-path-bound; T-recurrence
// is nonlinear (reset depends on spike) so no cross-T decomposition.

#define TAU 0.5f

__global__ __launch_bounds__(256) void lif_scan_kernel(
    const float2* __restrict__ inp,
    const float2* __restrict__ rec,
    float2* __restrict__ out,
    int n2,   // float2 lanes per timestep (B*N/2) = 65536
    int T)    // 100
{
    const int i = blockIdx.x * blockDim.x + threadIdx.x;
    if (i >= n2) return;

    float vx = 0.0f, vy = 0.0f;

    #pragma unroll 4
    for (int t = 0; t < T; ++t) {
        const size_t off = (size_t)t * (size_t)n2 + (size_t)i;
        const float2 x = inp[off];
        const float2 r = rec[off];

        // v*0.5 is exact (pow2), so fma contraction cannot change the
        // rounded result vs numpy's (v*0.5 + x) + r -> spike test exact.
        vx = vx * TAU + x.x + r.x;
        vy = vy * TAU + x.y + r.y;

        float2 s;
        s.x = (vx > 0.0f) ? 1.0f : 0.0f;
        s.y = (vy > 0.0f) ? 1.0f : 0.0f;

        vx = (vx > 0.0f) ? 0.0f : vx;
        vy = (vy > 0.0f) ? 0.0f : vy;

        out[off] = s;
    }
}

extern "C" void kernel_launch(void* const* d_in, const int* in_sizes, int n_in,
                              void* d_out, int out_size, void* d_ws, size_t ws_size,
                              hipStream_t stream) {
    const float* inp = (const float*)d_in[0];
    const float* rec = (const float*)d_in[1];
    float* out = (float*)d_out;

    const int T = 100;
    const int per_t = in_sizes[0] / T;   // B*N = 131072
    const int n2 = per_t / 2;            // 65536 float2 lanes

    const int block = 256;
    const int grid = (n2 + block - 1) / block;   // 256 blocks -> 1 per CU

    lif_scan_kernel<<<grid, block, 0, stream>>>(
        (const float2*)inp, (const float2*)rec, (float2*)out, n2, T);
}